// Round 1
// baseline (60.434 us; speedup 1.0000x reference)
//
#include <hip/hip_runtime.h>
#include <hip/hip_bf16.h>

// Spline1DInterpolant: out[b] = sum_i c[i] * u(|s_b - (i+1)|), s_b = (x_b - a)/h + 2,
// h = (b - a)/n. u is a cubic B-spline with support |t| <= 2, so only 4 terms
// (i+1 in {floor(s)-1 .. floor(s)+2}) are nonzero. Exact sparse evaluation.

__global__ __launch_bounds__(64) void spline1d_kernel(
    const float* __restrict__ x,
    const float* __restrict__ a,
    const float* __restrict__ b,
    const float* __restrict__ n,
    const float* __restrict__ c,
    float* __restrict__ out,
    int B, int C)
{
    int idx = blockIdx.x * blockDim.x + threadIdx.x;
    if (idx >= B) return;

    const float av = a[0];
    const float h  = (b[0] - av) / n[0];
    // Match reference op order: t = ((x - a)/h + 2) - (i+1)
    const float s = (x[idx] - av) / h + 2.0f;

    // Only i+1 in {floor(s)-1, floor(s), floor(s)+1, floor(s)+2} give t <= 2.
    const int i0 = (int)floorf(s) - 2;  // 0-based coefficient index of first term

    float acc = 0.0f;
#pragma unroll
    for (int k = 0; k < 4; ++k) {
        const int i = i0 + k;
        const int ic = min(max(i, 0), C - 1);     // safe load index
        const float t = fabsf(s - (float)(i + 1));
        const float t2 = t * t;
        const float inner = 4.0f - 6.0f * t2 + 3.0f * t2 * t;  // t <= 1
        const float om = 2.0f - t;
        const float outer = om * om * om;                      // 1 < t <= 2
        float u = (t <= 1.0f) ? inner : outer;
        // zero out-of-range i (reference sums only i in [0,C)) and t > 2
        u = (i >= 0 && i < C && t <= 2.0f) ? u : 0.0f;
        acc += c[ic] * u;
    }
    out[idx] = acc;
}

extern "C" void kernel_launch(void* const* d_in, const int* in_sizes, int n_in,
                              void* d_out, int out_size, void* d_ws, size_t ws_size,
                              hipStream_t stream) {
    const float* x = (const float*)d_in[0];  // [B,1] -> B floats
    const float* a = (const float*)d_in[1];  // [1]
    const float* b = (const float*)d_in[2];  // [1]
    const float* n = (const float*)d_in[3];  // [1]
    const float* c = (const float*)d_in[4];  // [C]
    float* out = (float*)d_out;              // [B]

    const int B = in_sizes[0];
    const int C = in_sizes[4];

    const int block = 64;
    const int grid = (B + block - 1) / block;
    spline1d_kernel<<<grid, block, 0, stream>>>(x, a, b, n, c, out, B, C);
}